// Round 14
// baseline (132.405 us; speedup 1.0000x reference)
//
#include <hip/hip_runtime.h>
#include <math.h>

#define BATCH  4
#define SEQL   4096
#define DMODEL 1024
#define NSTATE 64
#define LN_EPS 1e-5f
#define TB     8           // time rows processed per iteration (replay)
#define TBL    16          // time rows per iteration (local)

typedef unsigned short u16;
typedef unsigned int   u32;
typedef float f32x2 __attribute__((ext_vector_type(2)));

// Packed f32 FMA pair -> v_pk_fma_f32 (halves FMA issue count).
__device__ __forceinline__ f32x2 fma2(f32x2 a, f32x2 b, f32x2 c) {
#if __has_builtin(__builtin_elementwise_fma)
    return __builtin_elementwise_fma(a, b, c);
#else
    f32x2 d; d.x = fmaf(a.x, b.x, c.x); d.y = fmaf(a.y, b.y, c.y); return d;
#endif
}

__device__ __forceinline__ u16 f2bf(float x) {
    u32 b = __float_as_uint(x);
    b += 0x7FFF + ((b >> 16) & 1);       // round-to-nearest-even
    return (u16)(b >> 16);
}
__device__ __forceinline__ float bf2f(u16 h) {
    return __uint_as_float(((u32)h) << 16);
}
__device__ __forceinline__ u32 pack2bf(f32x2 v) {
    return (u32)f2bf(v.x) | ((u32)f2bf(v.y) << 16);
}
__device__ __forceinline__ f32x2 unpack2bf(u32 p) {
    f32x2 v; v.x = bf2f((u16)p); v.y = bf2f((u16)(p >> 16)); return v;
}

// ---------------------------------------------------------------------------
// k_local: block = (b, d-tile 128, chunk j). 4 waves; wave w owns states
// n in [16w,16w+16); lane l owns d-pair d0=dt*128+2l. Local scan, ZERO init;
// bf16 finals f[b][j][n][d] (paired u32 stores). float2 u loads.
// ---------------------------------------------------------------------------
__global__ __launch_bounds__(256) void k_local(const float* __restrict__ u,
                                               const float* __restrict__ A_log,
                                               const float* __restrict__ delta,
                                               u16* __restrict__ f,
                                               int NCH, int TCH) {
    __shared__ float r_lds[NSTATE];
    const int tid = threadIdx.x;
    const int w = tid >> 6, l = tid & 63;
    const int b   = blockIdx.x / (8 * NCH);
    const int rem = blockIdx.x % (8 * NCH);
    const int dt  = rem / NCH;
    const int j   = rem % NCH;
    const int n0  = w << 4;
    const int d0  = (dt << 7) | (l << 1);

    if (tid < NSTATE) r_lds[tid] = expf(delta[0] * -expf(A_log[tid]));
    __syncthreads();

    f32x2 r2[16], s2[16];
#pragma unroll
    for (int i = 0; i < 16; ++i) {
        const float rn = r_lds[n0 + i];
        r2[i].x = rn; r2[i].y = rn;
        s2[i] = (f32x2)(0.f, 0.f);
    }

    const float* ub = u + ((size_t)b * SEQL + (size_t)j * TCH) * DMODEL + d0;
    for (int tb = 0; tb < TCH / TBL; ++tb) {
        f32x2 ur[TBL];
#pragma unroll
        for (int t = 0; t < TBL; ++t)
            ur[t] = *(const f32x2*)&ub[(size_t)(tb * TBL + t) * DMODEL];
#pragma unroll
        for (int q = 0; q < 4; ++q) {
            f32x2 sa = s2[4*q], sb = s2[4*q+1], sc = s2[4*q+2], sd = s2[4*q+3];
            const f32x2 ra = r2[4*q], rb = r2[4*q+1], rc = r2[4*q+2], rd = r2[4*q+3];
#pragma unroll
            for (int t = 0; t < TBL; ++t) {
                const f32x2 u2 = ur[t];
                sa = fma2(ra, sa, u2);
                sb = fma2(rb, sb, u2);
                sc = fma2(rc, sc, u2);
                sd = fma2(rd, sd, u2);
            }
            s2[4*q] = sa; s2[4*q+1] = sb; s2[4*q+2] = sc; s2[4*q+3] = sd;
        }
    }
    u32* fb = (u32*)(f + (((size_t)b * NCH + j) * NSTATE + n0) * DMODEL + d0);
#pragma unroll
    for (int i = 0; i < 16; ++i)
        fb[(size_t)i * (DMODEL / 2)] = pack2bf(s2[i]);
}

// ---------------------------------------------------------------------------
// k_pass2: in-place boundary scan (bf16). f[b][j][n][d] (local finals) ->
// I[b][j][n][d] = state ENTERING chunk j. One thread per (b,n,d).
// ---------------------------------------------------------------------------
__global__ __launch_bounds__(256) void k_pass2(const float* __restrict__ A_log,
                                               const float* __restrict__ delta,
                                               u16* __restrict__ f,
                                               int NCH, int TCH) {
    const int tid = blockIdx.x * 256 + threadIdx.x;  // over B*N*D
    const int d = tid & (DMODEL - 1);
    const int n = (tid >> 10) & (NSTATE - 1);
    const int b = tid >> 16;
    const float A  = -expf(A_log[n]);
    const float rT = expf((float)TCH * delta[0] * A);
    float I = 0.f;
    u16* p = f + ((size_t)b * NCH * NSTATE + n) * DMODEL + d;
    const size_t stride = (size_t)NSTATE * DMODEL;
    for (int j = 0; j < NCH; ++j) {
        float tmp = bf2f(p[(size_t)j * stride]);
        p[(size_t)j * stride] = f2bf(I);
        I = fmaf(rT, I, tmp);
    }
}

// ---------------------------------------------------------------------------
// k_replay<ZBF16>: block = (b, d-tile 128, chunk j); wave w owns n in
// [16w,16w+16); lane l owns d-pair d0=dt*128+2l. Replays scan with initial
// state I (bf16); emits
//   z[t,d] = fal[d]*( sum_n C[d,n] s[n,t,d] + D[d] u[t,d] ) + reward[d]*(t==0)
// fal folded into c/D. All math packed over the d-pair (pk-FMA); float2 u
// loads. Cross-wave partials via double-buffered LDS, 1 barrier per TB tile.
// ---------------------------------------------------------------------------
template <bool ZBF16>
__global__ __launch_bounds__(256) void k_replay(const float* __restrict__ u,
                                                const float* __restrict__ A_log,
                                                const float* __restrict__ C,
                                                const float* __restrict__ Dvec,
                                                const float* __restrict__ delta,
                                                const u16* __restrict__ I,
                                                const float* __restrict__ fal,
                                                const float* __restrict__ rw,
                                                void* __restrict__ zout,
                                                int NCH, int TCH) {
    __shared__ float r_lds[NSTATE];
    __shared__ f32x2 part[2][4][TB][64];             // 32 KB double-buffered
    const int tid = threadIdx.x;
    const int w = tid >> 6, l = tid & 63;
    const int b   = blockIdx.x / (8 * NCH);
    const int rem = blockIdx.x % (8 * NCH);
    const int dt  = rem / NCH;
    const int j   = rem % NCH;
    const int n0  = w << 4;
    const int d0  = (dt << 7) | (l << 1);

    if (tid < NSTATE) r_lds[tid] = expf(delta[0] * -expf(A_log[tid]));
    __syncthreads();

    const float fa0 = fal[d0], fa1 = fal[d0 + 1];
    f32x2 r2[16], c2[16], s2[16];
#pragma unroll
    for (int i = 0; i < 16; ++i) {
        const float rn = r_lds[n0 + i];
        r2[i].x = rn; r2[i].y = rn;
        c2[i].x = fa0 * C[(size_t)d0       * NSTATE + n0 + i];
        c2[i].y = fa1 * C[(size_t)(d0 + 1) * NSTATE + n0 + i];
    }
    const u32* Ib = (const u32*)(I + (((size_t)b * NCH + j) * NSTATE + n0) * DMODEL + d0);
#pragma unroll
    for (int i = 0; i < 16; ++i)
        s2[i] = unpack2bf(Ib[(size_t)i * (DMODEL / 2)]);

    f32x2 Ddf2; Ddf2.x = Dvec[d0] * fa0; Ddf2.y = Dvec[d0 + 1] * fa1;
    f32x2 rw2;  rw2.x  = rw[d0];         rw2.y  = rw[d0 + 1];
    const float* ub = u + ((size_t)b * SEQL + (size_t)j * TCH) * DMODEL + d0;
    const size_t zoff = ((size_t)b * SEQL + (size_t)j * TCH) * DMODEL + d0;
    u32*   zb16 = (u32*)((u16*)zout + zoff);
    float* zb32 = (float*)zout + zoff;

    for (int tb = 0; tb < TCH / TB; ++tb) {
        const int pb = tb & 1;
        f32x2 ur[TB], zr[TB];
#pragma unroll
        for (int t = 0; t < TB; ++t) {
            ur[t] = *(const f32x2*)&ub[(size_t)(tb * TB + t) * DMODEL];
            zr[t] = (f32x2)(0.f, 0.f);
        }
#pragma unroll
        for (int q = 0; q < 4; ++q) {
            f32x2 sa = s2[4*q], sb = s2[4*q+1], sc = s2[4*q+2], sd = s2[4*q+3];
            const f32x2 ra = r2[4*q], rb = r2[4*q+1], rc = r2[4*q+2], rd = r2[4*q+3];
            const f32x2 ca = c2[4*q], cb = c2[4*q+1], cc = c2[4*q+2], cd = c2[4*q+3];
#pragma unroll
            for (int t = 0; t < TB; ++t) {
                const f32x2 u2 = ur[t];
                sa = fma2(ra, sa, u2);
                sb = fma2(rb, sb, u2);
                sc = fma2(rc, sc, u2);
                sd = fma2(rd, sd, u2);
                f32x2 a = fma2(ca, sa, zr[t]);
                a = fma2(cb, sb, a);
                a = fma2(cc, sc, a);
                zr[t] = fma2(cd, sd, a);
            }
            s2[4*q] = sa; s2[4*q+1] = sb; s2[4*q+2] = sc; s2[4*q+3] = sd;
        }
#pragma unroll
        for (int t = 0; t < TB; ++t) {
            f32x2 v = zr[t];
            if (w == 0) v = fma2(Ddf2, ur[t], v);    // fal-folded D-term, once
            part[pb][w][t][l] = v;
        }
        __syncthreads();
        // wave w finalizes rows [2w, 2w+2); no trailing barrier (dbuf).
#pragma unroll
        for (int k = 0; k < 2; ++k) {
            const int t = (w << 1) | k;
            f32x2 v;
            v.x = (part[pb][0][t][l].x + part[pb][1][t][l].x) +
                  (part[pb][2][t][l].x + part[pb][3][t][l].x);
            v.y = (part[pb][0][t][l].y + part[pb][1][t][l].y) +
                  (part[pb][2][t][l].y + part[pb][3][t][l].y);
            if (j == 0 && tb == 0 && t == 0) { v.x += rw2.x; v.y += rw2.y; }
            if (ZBF16) zb16[((size_t)(tb * TB + t) * DMODEL) / 2] = pack2bf(v);
            else       *(f32x2*)&zb32[(size_t)(tb * TB + t) * DMODEL] = v;
        }
    }
}

// ---------------------------------------------------------------------------
// k_ln<ZBF16>: LayerNorm over d. Reads z (bf16 ws or f32), writes f32 y.
// One block per (b,t) row, 4 channels per thread.
// ---------------------------------------------------------------------------
template <bool ZBF16>
__global__ __launch_bounds__(256) void k_ln(const void* __restrict__ zin,
                                            float* __restrict__ y,
                                            const float* __restrict__ gamma,
                                            const float* __restrict__ beta) {
    const int tid = threadIdx.x;
    float4 v;
    if (ZBF16) {
        const ushort4 h = ((const ushort4*)((const u16*)zin + (size_t)blockIdx.x * DMODEL))[tid];
        v.x = bf2f(h.x); v.y = bf2f(h.y); v.z = bf2f(h.z); v.w = bf2f(h.w);
    } else {
        v = ((const float4*)((const float*)zin + (size_t)blockIdx.x * DMODEL))[tid];
    }
    float sum = v.x + v.y + v.z + v.w;
    float sq  = v.x*v.x + v.y*v.y + v.z*v.z + v.w*v.w;
#pragma unroll
    for (int off = 32; off > 0; off >>= 1) {
        sum += __shfl_down(sum, off, 64);
        sq  += __shfl_down(sq,  off, 64);
    }
    __shared__ float red[8];
    const int wave = tid >> 6, lane = tid & 63;
    if (lane == 0) { red[wave] = sum; red[4 + wave] = sq; }
    __syncthreads();
    sum = red[0] + red[1] + red[2] + red[3];
    sq  = red[4] + red[5] + red[6] + red[7];
    const float mean = sum * (1.f / DMODEL);
    const float var  = sq * (1.f / DMODEL) - mean * mean;
    const float inv  = 1.f / sqrtf(var + LN_EPS);
    const float4 g  = ((const float4*)gamma)[tid];
    const float4 bb = ((const float4*)beta)[tid];
    float4 o;
    o.x = (v.x - mean) * inv * g.x + bb.x;
    o.y = (v.y - mean) * inv * g.y + bb.y;
    o.z = (v.z - mean) * inv * g.z + bb.z;
    o.w = (v.w - mean) * inv * g.w + bb.w;
    ((float4*)(y + (size_t)blockIdx.x * DMODEL))[tid] = o;
}

// ---------------------------------------------------------------------------
// k_state: final_state[b,n] = ((exp(dmean*A_n)-1)/A_safe_n) *
//                             sum_d B[n,d] * u[b, L-1, d]
// ---------------------------------------------------------------------------
__global__ __launch_bounds__(256) void k_state(const float* __restrict__ u,
                                               const float* __restrict__ A_log,
                                               const float* __restrict__ B,
                                               const float* __restrict__ delta,
                                               float* __restrict__ out) {
    const int n = blockIdx.x & 63;
    const int b = blockIdx.x >> 6;
    const int tid = threadIdx.x;
    const float* ul = u + ((size_t)b * SEQL + (SEQL - 1)) * DMODEL;
    const float* Bn = B + (size_t)n * DMODEL;
    float dot = 0.f, dsum = 0.f;
    for (int dd = tid; dd < DMODEL; dd += 256) {
        dot = fmaf(Bn[dd], ul[dd], dot);
        dsum += delta[dd];
    }
#pragma unroll
    for (int off = 32; off > 0; off >>= 1) {
        dot  += __shfl_down(dot,  off, 64);
        dsum += __shfl_down(dsum, off, 64);
    }
    __shared__ float red[8];
    const int wave = tid >> 6, lane = tid & 63;
    if (lane == 0) { red[wave] = dot; red[4 + wave] = dsum; }
    __syncthreads();
    if (tid == 0) {
        dot  = red[0] + red[1] + red[2] + red[3];
        dsum = red[4] + red[5] + red[6] + red[7];
        const float dmean = dsum * (1.f / DMODEL);
        const float A = -expf(A_log[n]);
        const float Abar = expf(dmean * A);
        const float Asafe = A + (A >= 0.f ? 1e-8f : -1e-8f);
        out[blockIdx.x] = ((Abar - 1.f) / Asafe) * dot;
    }
}

extern "C" void kernel_launch(void* const* d_in, const int* in_sizes, int n_in,
                              void* d_out, int out_size, void* d_ws, size_t ws_size,
                              hipStream_t stream) {
    const float* u     = (const float*)d_in[0];
    const float* A_log = (const float*)d_in[1];
    const float* B     = (const float*)d_in[2];
    const float* C     = (const float*)d_in[3];
    const float* Dv    = (const float*)d_in[4];
    const float* delta = (const float*)d_in[5];
    const float* gamma = (const float*)d_in[6];
    const float* beta  = (const float*)d_in[7];
    const float* fal   = (const float*)d_in[8];
    const float* rw    = (const float*)d_in[9];

    float* y  = (float*)d_out;
    float* st = y + (size_t)BATCH * SEQL * DMODEL;
    u16* f    = (u16*)d_ws;

    int NCH = 32;
    while (NCH > 4 && (size_t)BATCH * NCH * NSTATE * DMODEL * sizeof(u16) > ws_size)
        NCH >>= 1;
    const int TCH = SEQL / NCH;
    const int nb = BATCH * 8 * NCH;

    const size_t f_bytes = (size_t)BATCH * NCH * NSTATE * DMODEL * sizeof(u16);
    const size_t z_bytes = (size_t)BATCH * SEQL * DMODEL * sizeof(u16);
    const bool zbf16 = (f_bytes + z_bytes) <= ws_size;
    void* zbuf = zbf16 ? (void*)((char*)d_ws + f_bytes) : (void*)y;

    hipLaunchKernelGGL(k_local, dim3(nb), dim3(256), 0, stream, u, A_log, delta, f, NCH, TCH);
    hipLaunchKernelGGL(k_pass2, dim3(BATCH * NSTATE * DMODEL / 256), dim3(256), 0, stream,
                       A_log, delta, f, NCH, TCH);
    if (zbf16) {
        hipLaunchKernelGGL((k_replay<true>), dim3(nb), dim3(256), 0, stream,
                           u, A_log, C, Dv, delta, f, fal, rw, zbuf, NCH, TCH);
        hipLaunchKernelGGL((k_ln<true>), dim3(BATCH * SEQL), dim3(256), 0, stream,
                           zbuf, y, gamma, beta);
    } else {
        hipLaunchKernelGGL((k_replay<false>), dim3(nb), dim3(256), 0, stream,
                           u, A_log, C, Dv, delta, f, fal, rw, zbuf, NCH, TCH);
        hipLaunchKernelGGL((k_ln<false>), dim3(BATCH * SEQL), dim3(256), 0, stream,
                           zbuf, y, gamma, beta);
    }
    hipLaunchKernelGGL(k_state, dim3(BATCH * NSTATE), dim3(256), 0, stream,
                       u, A_log, B, delta, st);
}

// Round 15
// 125.738 us; speedup vs baseline: 1.0530x; 1.0530x over previous
//
#include <hip/hip_runtime.h>
#include <math.h>

#define BATCH  4
#define SEQL   4096
#define DMODEL 1024
#define NSTATE 64
#define LN_EPS 1e-5f
#define TB     16          // time rows processed per iteration

typedef unsigned short u16;
typedef unsigned int   u32;
typedef float f32x2 __attribute__((ext_vector_type(2)));

// Packed f32 FMA pair -> v_pk_fma_f32 (halves FMA issue count).
__device__ __forceinline__ f32x2 fma2(f32x2 a, f32x2 b, f32x2 c) {
#if __has_builtin(__builtin_elementwise_fma)
    return __builtin_elementwise_fma(a, b, c);
#else
    f32x2 d; d.x = fmaf(a.x, b.x, c.x); d.y = fmaf(a.y, b.y, c.y); return d;
#endif
}

__device__ __forceinline__ u16 f2bf(float x) {
    u32 b = __float_as_uint(x);
    b += 0x7FFF + ((b >> 16) & 1);       // round-to-nearest-even
    return (u16)(b >> 16);
}
__device__ __forceinline__ float bf2f(u16 h) {
    return __uint_as_float(((u32)h) << 16);
}

// ---------------------------------------------------------------------------
// k_local: block = (b, d-tile 64, chunk j). 4 waves; wave w owns states
// n in [16w, 16w+16); lane = d. Local scan, ZERO init; bf16 finals
// f[b][j][n][d]. Packed n-pair recurrence: 8 pk-FMA per t per thread.
// ---------------------------------------------------------------------------
__global__ __launch_bounds__(256) void k_local(const float* __restrict__ u,
                                               const float* __restrict__ A_log,
                                               const float* __restrict__ delta,
                                               u16* __restrict__ f,
                                               int NCH, int TCH) {
    __shared__ float r_lds[NSTATE];
    const int tid = threadIdx.x;
    const int w = tid >> 6, l = tid & 63;
    const int b   = blockIdx.x / (16 * NCH);
    const int rem = blockIdx.x % (16 * NCH);
    const int dt  = rem / NCH;
    const int j   = rem % NCH;
    const int n0  = w << 4;
    const int d   = (dt << 6) | l;

    if (tid < NSTATE) r_lds[tid] = expf(delta[0] * -expf(A_log[tid]));
    __syncthreads();

    f32x2 r2[8], s2[8];
#pragma unroll
    for (int p = 0; p < 8; ++p) {
        r2[p] = *(const f32x2*)&r_lds[n0 + 2 * p];
        s2[p] = (f32x2)(0.f, 0.f);
    }

    const float* ub = u + ((size_t)b * SEQL + (size_t)j * TCH) * DMODEL + d;
    for (int tb = 0; tb < TCH / TB; ++tb) {
        float ur[TB];
#pragma unroll
        for (int t = 0; t < TB; ++t)
            ur[t] = ub[(size_t)(tb * TB + t) * DMODEL];
#pragma unroll
        for (int q = 0; q < 4; ++q) {
            f32x2 sa = s2[2*q], sb = s2[2*q+1];
            const f32x2 ra = r2[2*q], rb = r2[2*q+1];
#pragma unroll
            for (int t = 0; t < TB; ++t) {
                f32x2 u2; u2.x = ur[t]; u2.y = ur[t];
                sa = fma2(ra, sa, u2);
                sb = fma2(rb, sb, u2);
            }
            s2[2*q] = sa; s2[2*q+1] = sb;
        }
    }
    u16* fb = f + (((size_t)b * NCH + j) * NSTATE + n0) * DMODEL + d;
#pragma unroll
    for (int p = 0; p < 8; ++p) {
        fb[(size_t)(2*p)     * DMODEL] = f2bf(s2[p].x);
        fb[(size_t)(2*p + 1) * DMODEL] = f2bf(s2[p].y);
    }
}

// ---------------------------------------------------------------------------
// k_pass2: in-place boundary scan (bf16). f[b][j][n][d] (local finals) ->
// I[b][j][n][d] = state ENTERING chunk j. One thread per (b,n,d).
// ---------------------------------------------------------------------------
__global__ __launch_bounds__(256) void k_pass2(const float* __restrict__ A_log,
                                               const float* __restrict__ delta,
                                               u16* __restrict__ f,
                                               int NCH, int TCH) {
    const int tid = blockIdx.x * 256 + threadIdx.x;  // over B*N*D
    const int d = tid & (DMODEL - 1);
    const int n = (tid >> 10) & (NSTATE - 1);
    const int b = tid >> 16;
    const float A  = -expf(A_log[n]);
    const float rT = expf((float)TCH * delta[0] * A);
    float I = 0.f;
    u16* p = f + ((size_t)b * NCH * NSTATE + n) * DMODEL + d;
    const size_t stride = (size_t)NSTATE * DMODEL;
    for (int j = 0; j < NCH; ++j) {
        float tmp = bf2f(p[(size_t)j * stride]);
        p[(size_t)j * stride] = f2bf(I);
        I = fmaf(rT, I, tmp);
    }
}

// ---------------------------------------------------------------------------
// k_replay<ZBF16>: block = (b, d-tile 64, chunk j); wave w owns n in
// [16w,16w+16), lane = d. Replays scan with initial state I (bf16); emits
//   z[t,d] = fal[d]*( sum_n C[d,n] s[n,t,d] + D[d] u[t,d] ) + reward[d]*(t==0)
// fal folded into c/D. u tile staged cooperatively in LDS (1 float4 load +
// 1 ds_write_b128 per thread per tile, replacing 16 scalar loads x4-wave
// redundancy). u tile + part both double-buffered -> ONE barrier per tile.
// ---------------------------------------------------------------------------
template <bool ZBF16>
__global__ __launch_bounds__(256) void k_replay(const float* __restrict__ u,
                                                const float* __restrict__ A_log,
                                                const float* __restrict__ C,
                                                const float* __restrict__ Dvec,
                                                const float* __restrict__ delta,
                                                const u16* __restrict__ I,
                                                const float* __restrict__ fal,
                                                const float* __restrict__ rw,
                                                void* __restrict__ zout,
                                                int NCH, int TCH) {
    __shared__ float r_lds[NSTATE];
    __shared__ float utile[2][TB][64];               // 8 KB double-buffered
    __shared__ float part[2][4][TB][64];             // 32 KB double-buffered
    const int tid = threadIdx.x;
    const int w = tid >> 6, l = tid & 63;
    const int b   = blockIdx.x / (16 * NCH);
    const int rem = blockIdx.x % (16 * NCH);
    const int dt  = rem / NCH;
    const int j   = rem % NCH;
    const int n0  = w << 4;
    const int d   = (dt << 6) | l;
    const int srow = tid >> 4, scol = (tid & 15) << 2;   // staging map

    if (tid < NSTATE) r_lds[tid] = expf(delta[0] * -expf(A_log[tid]));

    const float fad = fal[d];
    f32x2 r2[8], c2[8], s2[8];
#pragma unroll
    for (int p = 0; p < 8; ++p)
        r2[p] = *(const f32x2*)&r_lds[n0 + 2 * p];   // after barrier below
#pragma unroll
    for (int p = 0; p < 8; ++p) {
        c2[p].x = fad * C[(size_t)d * NSTATE + n0 + 2*p];
        c2[p].y = fad * C[(size_t)d * NSTATE + n0 + 2*p + 1];
    }
    const u16* Ib = I + (((size_t)b * NCH + j) * NSTATE + n0) * DMODEL + d;
#pragma unroll
    for (int p = 0; p < 8; ++p) {
        s2[p].x = bf2f(Ib[(size_t)(2*p)     * DMODEL]);
        s2[p].y = bf2f(Ib[(size_t)(2*p + 1) * DMODEL]);
    }

    const float Ddf = Dvec[d] * fad;
    const float rwd = rw[d];
    const float* ustage = u + ((size_t)b * SEQL + (size_t)j * TCH) * DMODEL + (dt << 6);
    const size_t zoff = ((size_t)b * SEQL + (size_t)j * TCH) * DMODEL + d;
    u16*   zb16 = (u16*)zout + zoff;
    float* zb32 = (float*)zout + zoff;

    // prologue: stage tile 0 (and re-read r_lds after this barrier)
    *(float4*)&utile[0][srow][scol] =
        *(const float4*)&ustage[(size_t)srow * DMODEL + scol];
    __syncthreads();
#pragma unroll
    for (int p = 0; p < 8; ++p)
        r2[p] = *(const f32x2*)&r_lds[n0 + 2 * p];

    const int ntb = TCH / TB;
    for (int tb = 0; tb < ntb; ++tb) {
        const int pb = tb & 1;
        // stage next tile into the other buffer (overlaps with compute)
        if (tb + 1 < ntb)
            *(float4*)&utile[pb ^ 1][srow][scol] =
                *(const float4*)&ustage[(size_t)((tb + 1) * TB + srow) * DMODEL + scol];

        float ur[TB];
        f32x2 zr2[TB];
#pragma unroll
        for (int t = 0; t < TB; ++t) {
            ur[t] = utile[pb][t][l];                 // conflict-free ds_read
            zr2[t] = (f32x2)(0.f, 0.f);
        }
#pragma unroll
        for (int q = 0; q < 4; ++q) {
            f32x2 sa = s2[2*q], sb = s2[2*q+1];
            const f32x2 ra = r2[2*q], rb = r2[2*q+1];
            const f32x2 ca = c2[2*q], cb = c2[2*q+1];
#pragma unroll
            for (int t = 0; t < TB; ++t) {
                f32x2 u2; u2.x = ur[t]; u2.y = ur[t];
                sa = fma2(ra, sa, u2);
                sb = fma2(rb, sb, u2);
                zr2[t] = fma2(ca, sa, zr2[t]);
                zr2[t] = fma2(cb, sb, zr2[t]);
            }
            s2[2*q] = sa; s2[2*q+1] = sb;
        }
#pragma unroll
        for (int t = 0; t < TB; ++t) {
            float v = zr2[t].x + zr2[t].y;
            if (w == 0) v = fmaf(Ddf, ur[t], v);     // fal-folded D-term, once
            part[pb][w][t][l] = v;
        }
        __syncthreads();
        // wave w finalizes rows [4w, 4w+4); no trailing barrier (dbuf).
#pragma unroll
        for (int k = 0; k < 4; ++k) {
            const int t = (w << 2) | k;
            float v = (part[pb][0][t][l] + part[pb][1][t][l]) +
                      (part[pb][2][t][l] + part[pb][3][t][l]);
            if (j == 0 && tb == 0 && t == 0) v += rwd;
            if (ZBF16) zb16[(size_t)(tb * TB + t) * DMODEL] = f2bf(v);
            else       zb32[(size_t)(tb * TB + t) * DMODEL] = v;
        }
    }
}

// ---------------------------------------------------------------------------
// k_ln<ZBF16>: LayerNorm over d. Reads z (bf16 ws or f32), writes f32 y.
// One block per (b,t) row, 4 channels per thread.
// ---------------------------------------------------------------------------
template <bool ZBF16>
__global__ __launch_bounds__(256) void k_ln(const void* __restrict__ zin,
                                            float* __restrict__ y,
                                            const float* __restrict__ gamma,
                                            const float* __restrict__ beta) {
    const int tid = threadIdx.x;
    float4 v;
    if (ZBF16) {
        const ushort4 h = ((const ushort4*)((const u16*)zin + (size_t)blockIdx.x * DMODEL))[tid];
        v.x = bf2f(h.x); v.y = bf2f(h.y); v.z = bf2f(h.z); v.w = bf2f(h.w);
    } else {
        v = ((const float4*)((const float*)zin + (size_t)blockIdx.x * DMODEL))[tid];
    }
    float sum = v.x + v.y + v.z + v.w;
    float sq  = v.x*v.x + v.y*v.y + v.z*v.z + v.w*v.w;
#pragma unroll
    for (int off = 32; off > 0; off >>= 1) {
        sum += __shfl_down(sum, off, 64);
        sq  += __shfl_down(sq,  off, 64);
    }
    __shared__ float red[8];
    const int wave = tid >> 6, lane = tid & 63;
    if (lane == 0) { red[wave] = sum; red[4 + wave] = sq; }
    __syncthreads();
    sum = red[0] + red[1] + red[2] + red[3];
    sq  = red[4] + red[5] + red[6] + red[7];
    const float mean = sum * (1.f / DMODEL);
    const float var  = sq * (1.f / DMODEL) - mean * mean;
    const float inv  = 1.f / sqrtf(var + LN_EPS);
    const float4 g  = ((const float4*)gamma)[tid];
    const float4 bb = ((const float4*)beta)[tid];
    float4 o;
    o.x = (v.x - mean) * inv * g.x + bb.x;
    o.y = (v.y - mean) * inv * g.y + bb.y;
    o.z = (v.z - mean) * inv * g.z + bb.z;
    o.w = (v.w - mean) * inv * g.w + bb.w;
    ((float4*)(y + (size_t)blockIdx.x * DMODEL))[tid] = o;
}

// ---------------------------------------------------------------------------
// k_state: final_state[b,n] = ((exp(dmean*A_n)-1)/A_safe_n) *
//                             sum_d B[n,d] * u[b, L-1, d]
// ---------------------------------------------------------------------------
__global__ __launch_bounds__(256) void k_state(const float* __restrict__ u,
                                               const float* __restrict__ A_log,
                                               const float* __restrict__ B,
                                               const float* __restrict__ delta,
                                               float* __restrict__ out) {
    const int n = blockIdx.x & 63;
    const int b = blockIdx.x >> 6;
    const int tid = threadIdx.x;
    const float* ul = u + ((size_t)b * SEQL + (SEQL - 1)) * DMODEL;
    const float* Bn = B + (size_t)n * DMODEL;
    float dot = 0.f, dsum = 0.f;
    for (int dd = tid; dd < DMODEL; dd += 256) {
        dot = fmaf(Bn[dd], ul[dd], dot);
        dsum += delta[dd];
    }
#pragma unroll
    for (int off = 32; off > 0; off >>= 1) {
        dot  += __shfl_down(dot,  off, 64);
        dsum += __shfl_down(dsum, off, 64);
    }
    __shared__ float red[8];
    const int wave = tid >> 6, lane = tid & 63;
    if (lane == 0) { red[wave] = dot; red[4 + wave] = dsum; }
    __syncthreads();
    if (tid == 0) {
        dot  = red[0] + red[1] + red[2] + red[3];
        dsum = red[4] + red[5] + red[6] + red[7];
        const float dmean = dsum * (1.f / DMODEL);
        const float A = -expf(A_log[n]);
        const float Abar = expf(dmean * A);
        const float Asafe = A + (A >= 0.f ? 1e-8f : -1e-8f);
        out[blockIdx.x] = ((Abar - 1.f) / Asafe) * dot;
    }
}

extern "C" void kernel_launch(void* const* d_in, const int* in_sizes, int n_in,
                              void* d_out, int out_size, void* d_ws, size_t ws_size,
                              hipStream_t stream) {
    const float* u     = (const float*)d_in[0];
    const float* A_log = (const float*)d_in[1];
    const float* B     = (const float*)d_in[2];
    const float* C     = (const float*)d_in[3];
    const float* Dv    = (const float*)d_in[4];
    const float* delta = (const float*)d_in[5];
    const float* gamma = (const float*)d_in[6];
    const float* beta  = (const float*)d_in[7];
    const float* fal   = (const float*)d_in[8];
    const float* rw    = (const float*)d_in[9];

    float* y  = (float*)d_out;
    float* st = y + (size_t)BATCH * SEQL * DMODEL;
    u16* f    = (u16*)d_ws;

    int NCH = 32;
    while (NCH > 4 && (size_t)BATCH * NCH * NSTATE * DMODEL * sizeof(u16) > ws_size)
        NCH >>= 1;
    const int TCH = SEQL / NCH;
    const int nb = BATCH * 16 * NCH;

    const size_t f_bytes = (size_t)BATCH * NCH * NSTATE * DMODEL * sizeof(u16);
    const size_t z_bytes = (size_t)BATCH * SEQL * DMODEL * sizeof(u16);
    const bool zbf16 = (f_bytes + z_bytes) <= ws_size;
    void* zbuf = zbf16 ? (void*)((char*)d_ws + f_bytes) : (void*)y;

    hipLaunchKernelGGL(k_local, dim3(nb), dim3(256), 0, stream, u, A_log, delta, f, NCH, TCH);
    hipLaunchKernelGGL(k_pass2, dim3(BATCH * NSTATE * DMODEL / 256), dim3(256), 0, stream,
                       A_log, delta, f, NCH, TCH);
    if (zbf16) {
        hipLaunchKernelGGL((k_replay<true>), dim3(nb), dim3(256), 0, stream,
                           u, A_log, C, Dv, delta, f, fal, rw, zbuf, NCH, TCH);
        hipLaunchKernelGGL((k_ln<true>), dim3(BATCH * SEQL), dim3(256), 0, stream,
                           zbuf, y, gamma, beta);
    } else {
        hipLaunchKernelGGL((k_replay<false>), dim3(nb), dim3(256), 0, stream,
                           u, A_log, C, Dv, delta, f, fal, rw, zbuf, NCH, TCH);
        hipLaunchKernelGGL((k_ln<false>), dim3(BATCH * SEQL), dim3(256), 0, stream,
                           zbuf, y, gamma, beta);
    }
    hipLaunchKernelGGL(k_state, dim3(BATCH * NSTATE), dim3(256), 0, stream,
                       u, A_log, B, delta, st);
}